// Round 7
// baseline (127.624 us; speedup 1.0000x reference)
//
#include <hip/hip_runtime.h>
#include <hip/hip_bf16.h>
#include <stdint.h>

// KANExpert: out[b,j] = sum_{i,g} basis(x[b,i])[g] * coeff[i,j,g] * scaling[i,j]
// == GEMM M=4096(batch) N=512(out) K=4096(=512 in_dim * 8 basis), bf16 MFMA.
//
// R7: R6's ring pipeline (depth-3 LDS, raw s_barrier + manual vmcnt) matched
// prediction. Now kill the Ag detour: basis A-tiles are computed IN-KERNEL
// from x (1 float -> 8 bf16 via 64-bit shift placement, ~40 VALU inst) and
// ds_written into the ring stage while B(k+3)'s global_load_lds fly. Prep is
// W-pack only. Waits: steady vmcnt(7)+lgkm(0); peeled head 4/5/6, tail 7/4/1
// (in-order vmcnt retirement; B(k+3)=2 ops + x(k+4)=1 op per iter).

#define BATCH   4096
#define IN_DIM  512
#define OUT_DIM 512
#define KDIM    (IN_DIM * 8)   // 4096
#define NKT     (KDIM / 64)    // 64 K-tiles

typedef short short8 __attribute__((ext_vector_type(8)));
typedef float f32x4  __attribute__((ext_vector_type(4)));

// s_waitcnt simm16: vmcnt[3:0] | expcnt[6:4] | lgkmcnt[11:8]  (exp=7 = don't care)
#define W_VM4_LG0 0x074
#define W_VM5_LG0 0x075
#define W_VM6_LG0 0x076
#define W_VM7_LG0 0x077
#define W_VM1_LG0 0x071

// float -> bf16 bits, round-to-nearest-even
__device__ __forceinline__ unsigned int f2bf(float f) {
  union { float f; unsigned int u; } v; v.f = f;
  unsigned int r = v.u + 0x7FFFu + ((v.u >> 16) & 1u);
  return r >> 16;
}

// All 8 basis values of one (b,i): window w0..w3 placed at slots m-3..m via a
// 64-bit shift (negative shift = right). Slots outside window are zero-filled
// by the shift. m = clamp(floor((x+1)*2.5), 0, 4).
__device__ __forceinline__ short8 basis_pack8(float xv) {
  float t = __builtin_fmaf(xv, 2.5f, 2.5f);
  int m = (int)t;
  m = m < 0 ? 0 : (m > 4 ? 4 : m);
  float u  = t - (float)m;
  float u2 = u * u, u3 = u2 * u, om = 1.0f - u;
  float w0 = om * om * om * (1.0f / 6.0f);
  float w1 = (3.0f * u3 - 6.0f * u2 + 4.0f) * (1.0f / 6.0f);
  float w2 = (-3.0f * u3 + 3.0f * u2 + 3.0f * u + 1.0f) * (1.0f / 6.0f);
  float w3 = u3 * (1.0f / 6.0f);
  uint64_t wp = (uint64_t)f2bf(w0) | ((uint64_t)f2bf(w1) << 16)
              | ((uint64_t)f2bf(w2) << 32) | ((uint64_t)f2bf(w3) << 48);
  int sh = (m - 3) * 16;
  uint64_t lo, hi;
  if (sh >= 0) { lo = wp << sh; hi = (sh > 0) ? (wp >> (64 - sh)) : 0ull; }
  else         { lo = wp >> (-sh); hi = 0ull; }
  union { uint64_t q[2]; short8 s; } r;
  r.q[0] = lo; r.q[1] = hi;
  return r.s;
}

__device__ __forceinline__ void async_load16(const void* g, void* l) {
  __builtin_amdgcn_global_load_lds(
      (__attribute__((address_space(1))) void*)(uintptr_t)g,
      (__attribute__((address_space(3))) void*)(unsigned int)(uintptr_t)l,
      16, 0, 0);
}

// ---- precompute W^T: Wt[j*4096 + i*8 + g] = bf16(coeff[i,j,g]*scaling[i,j])
__global__ void kan_prep(const float* __restrict__ coeff,
                         const float* __restrict__ scaling,
                         unsigned short* __restrict__ Wt) {
  int idx = blockIdx.x * 256 + threadIdx.x;  // i*512 + j
  int i = idx >> 9, j = idx & 511;
  float s = scaling[idx];
  const float4* cp = reinterpret_cast<const float4*>(coeff) + (size_t)idx * 2;
  float4 c0 = cp[0], c1 = cp[1];
  short8 h;
  h[0] = (short)f2bf(c0.x * s); h[1] = (short)f2bf(c0.y * s);
  h[2] = (short)f2bf(c0.z * s); h[3] = (short)f2bf(c0.w * s);
  h[4] = (short)f2bf(c1.x * s); h[5] = (short)f2bf(c1.y * s);
  h[6] = (short)f2bf(c1.z * s); h[7] = (short)f2bf(c1.w * s);
  *reinterpret_cast<short8*>(Wt + (size_t)j * KDIM + i * 8) = h;
}

// ---- fused-basis pipelined 64x64x64 GEMM, depth-3 LDS ring ---------------
// 256 thr = 4 waves (2x2), wave tile 32x32 (2x2 of 16x16x32). 1-D grid of
// 512 blocks: row-tile = b%64 (XCD = b%8 -> row's x + out pinned to one L2),
// col-tile = b/64. Per iter k (stage st = k%3):
//   s_waitcnt vmcnt(7) lgkmcnt(0); s_barrier    -- B(k) landed, A-writes pub.
//   compute(st)                                 -- 16 MFMA
//   s_barrier                                   -- stage st recyclable
//   issueB(k+3,st); xload(k+4); computeA(k+3,st)-- basis overlaps B-flight
__global__ __launch_bounds__(256, 2)
void kan_gemm_p(const float* __restrict__ x,
                const unsigned short* __restrict__ Wt,
                float* __restrict__ out) {
  __shared__ unsigned short As[3][64 * 64];   // 3 x 8 KB
  __shared__ unsigned short Bs[3][64 * 64];   // 3 x 8 KB

  const int tid  = threadIdx.x;
  const int lane = tid & 63;
  const int wid  = tid >> 6;
  const int wm = wid >> 1, wn = wid & 1;
  const int ln = lane & 15, quad = lane >> 4;

  const int b    = blockIdx.x;
  const int row0 = (b & 63) * 64;           // XCD-pinning key (XCD = b%8)
  const int col0 = (b >> 6) * 64;

  f32x4 acc[2][2] = {};

  const int lr = lane >> 3;                 // B staging row within 8-row inst
  const int cg = (lane & 7) ^ lr;           // XOR-swizzled 16B chunk to fetch

  const unsigned short* bRow = Wt + (size_t)(col0 + wid * 16 + lr) * KDIM + cg * 8;

  // A-compute assignment: thread -> row rn, chunks (wid*2, wid*2+1)
  const int rn = lane;                       // 0..63
  const float* xRow = x + (size_t)(row0 + rn) * IN_DIM + wid * 2;
  const int sw0 = ((wid * 2)     ^ (rn & 7)) * 8;
  const int sw1 = ((wid * 2 + 1) ^ (rn & 7)) * 8;

  auto issueB = [&](int kt, int st) {
    const int k0 = kt * 64;
#pragma unroll
    for (int t = 0; t < 2; ++t) {
      const int rbase = wid * 16 + t * 8;                       // wave-uniform
      async_load16(bRow + (size_t)t * 8 * KDIM + k0, &Bs[st][rbase * 64]);
    }
  };

  auto computeA = [&](float2 xv, int st) {
    short8 h0 = basis_pack8(xv.x);
    short8 h1 = basis_pack8(xv.y);
    *reinterpret_cast<short8*>(&As[st][rn * 64 + sw0]) = h0;
    *reinterpret_cast<short8*>(&As[st][rn * 64 + sw1]) = h1;
  };

  auto loadx = [&](int kt) -> float2 {
    return *reinterpret_cast<const float2*>(xRow + kt * 8);
  };

  auto compute = [&](int st) {
#pragma unroll
    for (int kk = 0; kk < 2; ++kk) {
      short8 af[2], bfr[2];
#pragma unroll
      for (int mt = 0; mt < 2; ++mt) {
        const int r    = wm * 32 + mt * 16 + ln;
        const int slot = (kk * 4 + quad) ^ (r & 7);
        af[mt] = *reinterpret_cast<const short8*>(&As[st][r * 64 + slot * 8]);
      }
#pragma unroll
      for (int nt = 0; nt < 2; ++nt) {
        const int c    = wn * 32 + nt * 16 + ln;
        const int slot = (kk * 4 + quad) ^ (c & 7);
        bfr[nt] = *reinterpret_cast<const short8*>(&Bs[st][c * 64 + slot * 8]);
      }
#pragma unroll
      for (int mt = 0; mt < 2; ++mt)
#pragma unroll
        for (int nt = 0; nt < 2; ++nt)
          acc[mt][nt] = __builtin_amdgcn_mfma_f32_16x16x32_bf16(af[mt], bfr[nt], acc[mt][nt], 0, 0, 0);
    }
  };

  // ---- prologue: x0..x3 then B0..B2; A0..A2 computed while B's fly -------
  float2 x0 = loadx(0), x1 = loadx(1), x2 = loadx(2), xcur = loadx(3);
  issueB(0, 0); issueB(1, 1); issueB(2, 2);
  computeA(x0, 0); computeA(x1, 1); computeA(x2, 2);

  // ---- peeled heads (vm counts: ops-younger-than-B(k) = 4,5,6) -----------
  int st = 0;
  // k=0
  __builtin_amdgcn_s_waitcnt(W_VM4_LG0); __builtin_amdgcn_s_barrier();
  compute(0); __builtin_amdgcn_s_barrier();
  issueB(3, 0); { float2 xn = loadx(4); computeA(xcur, 0); xcur = xn; }
  // k=1
  __builtin_amdgcn_s_waitcnt(W_VM5_LG0); __builtin_amdgcn_s_barrier();
  compute(1); __builtin_amdgcn_s_barrier();
  issueB(4, 1); { float2 xn = loadx(5); computeA(xcur, 1); xcur = xn; }
  // k=2
  __builtin_amdgcn_s_waitcnt(W_VM6_LG0); __builtin_amdgcn_s_barrier();
  compute(2); __builtin_amdgcn_s_barrier();
  issueB(5, 2); { float2 xn = loadx(6); computeA(xcur, 2); xcur = xn; }

  // ---- steady loop k=3..60 (vmcnt(7): B(k+1..k+3)=6 + x(k+4)=1 allowed) --
  st = 0;
  for (int kt = 3; kt <= NKT - 4; ++kt) {
    __builtin_amdgcn_s_waitcnt(W_VM7_LG0);
    __builtin_amdgcn_s_barrier();
    compute(st);
    __builtin_amdgcn_s_barrier();
    issueB(kt + 3, st);
    const int kx = (kt + 4 < NKT) ? (kt + 4) : (NKT - 1);  // dup at tail keeps counts fixed
    float2 xn = loadx(kx);
    computeA(xcur, st);
    xcur = xn;
    st = (st == 2) ? 0 : st + 1;
  }

  // ---- tail: tiles 61, 62, 63 (vm 7 / 4 / 1) -----------------------------
  __builtin_amdgcn_s_waitcnt(W_VM7_LG0); __builtin_amdgcn_s_barrier();
  compute(st); st = (st == 2) ? 0 : st + 1;
  __builtin_amdgcn_s_waitcnt(W_VM4_LG0); __builtin_amdgcn_s_barrier();
  compute(st); st = (st == 2) ? 0 : st + 1;
  __builtin_amdgcn_s_waitcnt(W_VM1_LG0); __builtin_amdgcn_s_barrier();
  compute(st);

  // C/D layout: col = lane&15, row = quad*4 + reg  (m89/m91-verified)
#pragma unroll
  for (int mt = 0; mt < 2; ++mt)
#pragma unroll
    for (int nt = 0; nt < 2; ++nt) {
      const int col = col0 + wn * 32 + nt * 16 + ln;
#pragma unroll
      for (int r = 0; r < 4; ++r) {
        const int row = row0 + wm * 32 + mt * 16 + quad * 4 + r;
        out[(size_t)row * OUT_DIM + col] = acc[mt][nt][r];
      }
    }
}

// ---- fallback (no ws): on-the-fly staging, 64-tile, direct store ---------
__global__ __launch_bounds__(256, 2)
void kan_gemm_fb(const float* __restrict__ x, const float* __restrict__ coeff,
                 const float* __restrict__ scaling, float* __restrict__ out) {
  __shared__ unsigned short As[64 * 64];
  __shared__ unsigned short Bs[64 * 64];

  const int tid  = threadIdx.x;
  const int lane = tid & 63;
  const int wid  = tid >> 6;
  const int wm = wid >> 1, wn = wid & 1;
  const int ln = lane & 15, quad = lane >> 4;
  const int row0 = blockIdx.y * 64;
  const int col0 = blockIdx.x * 64;

  f32x4 acc[2][2] = {};

  for (int kt = 0; kt < KDIM / 64; ++kt) {
#pragma unroll
    for (int pp = 0; pp < 2; ++pp) {
      const int p  = tid + pp * 256;
      const int rn = p & 63;
      const int il = p >> 6;
      const int sw = ((il ^ (rn & 7)) * 8);
      short8 ha = basis_pack8(x[(size_t)(row0 + rn) * IN_DIM + kt * 8 + il]);
      *reinterpret_cast<short8*>(&As[rn * 64 + sw]) = ha;
      const float* cbase = coeff + (size_t)(kt * 8 + il) * 4096 + (size_t)(col0 + rn) * 8;
      float4 c0 = reinterpret_cast<const float4*>(cbase)[0];
      float4 c1 = reinterpret_cast<const float4*>(cbase)[1];
      float s = scaling[(size_t)(kt * 8 + il) * OUT_DIM + col0 + rn];
      short8 hb;
      hb[0] = (short)f2bf(c0.x * s); hb[1] = (short)f2bf(c0.y * s);
      hb[2] = (short)f2bf(c0.z * s); hb[3] = (short)f2bf(c0.w * s);
      hb[4] = (short)f2bf(c1.x * s); hb[5] = (short)f2bf(c1.y * s);
      hb[6] = (short)f2bf(c1.z * s); hb[7] = (short)f2bf(c1.w * s);
      *reinterpret_cast<short8*>(&Bs[rn * 64 + sw]) = hb;
    }
    __syncthreads();
#pragma unroll
    for (int kk = 0; kk < 2; ++kk) {
      short8 af[2], bfr[2];
#pragma unroll
      for (int mt = 0; mt < 2; ++mt) {
        const int r  = wm * 32 + mt * 16 + ln;
        const int pc = (kk * 4 + quad) ^ (r & 7);
        af[mt] = *reinterpret_cast<const short8*>(&As[r * 64 + pc * 8]);
      }
#pragma unroll
      for (int nt = 0; nt < 2; ++nt) {
        const int c  = wn * 32 + nt * 16 + ln;
        const int pc = (kk * 4 + quad) ^ (c & 7);
        bfr[nt] = *reinterpret_cast<const short8*>(&Bs[c * 64 + pc * 8]);
      }
#pragma unroll
      for (int mt = 0; mt < 2; ++mt)
#pragma unroll
        for (int nt = 0; nt < 2; ++nt)
          acc[mt][nt] = __builtin_amdgcn_mfma_f32_16x16x32_bf16(af[mt], bfr[nt], acc[mt][nt], 0, 0, 0);
    }
    __syncthreads();
  }
#pragma unroll
  for (int mt = 0; mt < 2; ++mt)
#pragma unroll
    for (int nt = 0; nt < 2; ++nt) {
      const int col = col0 + wn * 32 + nt * 16 + ln;
#pragma unroll
      for (int r = 0; r < 4; ++r) {
        const int row = row0 + wm * 32 + mt * 16 + quad * 4 + r;
        out[(size_t)row * OUT_DIM + col] = acc[mt][nt][r];
      }
    }
}

// ---- launch ------------------------------------------------------------
extern "C" void kernel_launch(void* const* d_in, const int* in_sizes, int n_in,
                              void* d_out, int out_size, void* d_ws, size_t ws_size,
                              hipStream_t stream) {
  const float* x       = (const float*)d_in[0];
  const float* coeff   = (const float*)d_in[1];
  const float* scaling = (const float*)d_in[2];
  float* out = (float*)d_out;

  const size_t needW = (size_t)OUT_DIM * KDIM * 2;   // 4 MB bf16 W^T

  if (ws_size >= needW) {
    unsigned short* Wt = (unsigned short*)d_ws;
    kan_prep<<<(IN_DIM * OUT_DIM) / 256, 256, 0, stream>>>(coeff, scaling, Wt);
    kan_gemm_p<<<(BATCH / 64) * (OUT_DIM / 64), 256, 0, stream>>>(x, Wt, out);
  } else {
    kan_gemm_fb<<<dim3(OUT_DIM / 64, BATCH / 64), 256, 0, stream>>>(x, coeff, scaling, out);
  }
}

// Round 8
// 115.111 us; speedup vs baseline: 1.1087x; 1.1087x over previous
//
#include <hip/hip_runtime.h>
#include <hip/hip_bf16.h>
#include <stdint.h>

// KANExpert: out[b,j] = sum_{i,g} basis(x[b,i])[g] * coeff[i,j,g] * scaling[i,j]
// == GEMM M=4096(batch) N=512(out) K=4096(=512 in_dim * 8 basis), bf16 MFMA.
//
// R8: R7's fused basis fixed traffic (FETCH 133->20 MB) but put ~160 cyc of
// dependent VALU on the 2-barrier critical path (gemm 61 us, VALUBusy 38%).
// Restructure: ONE barrier/iter, depth-4 LDS rings (A,B,X), and ALL vm-ops are
// resultless global_load_lds (B tiles AND x tiles) so the compiler cannot
// insert dependent vmcnt waits -- our manual vmcnt(6) is the only VM wait.
// Iter k: wait vm(6) lgkm(0); barrier; issue X(k+5),B(k+3); computeA(k+3)
// (x from LDS X-stage, ~28 VALU inst/elem); compute(k). Uniform counts via
// index clamping (no peel). LDS 72 KB, 2 blocks/CU, 67 barriers total.

#define BATCH   4096
#define IN_DIM  512
#define OUT_DIM 512
#define KDIM    (IN_DIM * 8)   // 4096
#define NKT     (KDIM / 64)    // 64 K-tiles

typedef short short8 __attribute__((ext_vector_type(8)));
typedef float f32x4  __attribute__((ext_vector_type(4)));

// s_waitcnt simm16 (gfx9): vmcnt[3:0] | expcnt[6:4] | lgkmcnt[11:8]
#define W_VM6_LG0  0x076
#define W_VM8_LG0  0x078
#define W_VM10_LG0 0x07A

// float -> bf16 bits, round-to-nearest-even (used in prep only)
__device__ __forceinline__ unsigned int f2bf(float f) {
  union { float f; unsigned int u; } v; v.f = f;
  unsigned int r = v.u + 0x7FFFu + ((v.u >> 16) & 1u);
  return r >> 16;
}

// All 8 basis values of one (b,i), truncating bf16 pack (~28 VALU inst).
// Uniform cubic B-spline, h=0.4: m = min((int)(x*2.5+2.5), 4), u in [0,1];
// window w0..w3 placed at slots m-3..m via branchless 64-bit shift.
__device__ __forceinline__ short8 basis_pack8(float xv) {
  float t = __builtin_fmaf(xv, 2.5f, 2.5f);
  int m = (int)t;                       // t >= 0 -> trunc == floor
  m = m > 4 ? 4 : m;
  float u  = t - (float)m;
  float u2 = u * u, u3 = u2 * u, om = 1.0f - u;
  float om2 = om * om;
  float w0 = om2 * om * (1.0f / 6.0f);
  float w1 = __builtin_fmaf(u3, 0.5f, __builtin_fmaf(u2, -1.0f, 2.0f / 3.0f));
  float s  = (u2 - u3) + u;
  float w2 = __builtin_fmaf(s, 0.5f, 1.0f / 6.0f);
  float w3 = u3 * (1.0f / 6.0f);
  // truncating bf16 pack: take high 16 bits of each float via v_perm
  unsigned d0 = __builtin_amdgcn_perm(__float_as_uint(w1), __float_as_uint(w0), 0x07060302u);
  unsigned d1 = __builtin_amdgcn_perm(__float_as_uint(w3), __float_as_uint(w2), 0x07060302u);
  uint64_t wp = ((uint64_t)d1 << 32) | d0;
  int sh = m * 16 - 48;                 // {-48,-32,-16,0,16}
  uint64_t lo = (sh >= 0) ? (wp << sh) : (wp >> (-sh));
  unsigned hi = (sh > 0) ? (unsigned)(wp >> (64 - sh)) : 0u;
  union { unsigned d[4]; short8 s8; } r;
  r.d[0] = (unsigned)lo; r.d[1] = (unsigned)(lo >> 32); r.d[2] = hi; r.d[3] = 0u;
  return r.s8;
}

__device__ __forceinline__ void async_load16(const void* g, void* l) {
  __builtin_amdgcn_global_load_lds(
      (__attribute__((address_space(1))) void*)(uintptr_t)g,
      (__attribute__((address_space(3))) void*)(unsigned int)(uintptr_t)l,
      16, 0, 0);
}
__device__ __forceinline__ void async_load4(const void* g, void* l) {
  __builtin_amdgcn_global_load_lds(
      (__attribute__((address_space(1))) void*)(uintptr_t)g,
      (__attribute__((address_space(3))) void*)(unsigned int)(uintptr_t)l,
      4, 0, 0);
}

// ---- precompute W^T: Wt[j*4096 + i*8 + g] = bf16(coeff[i,j,g]*scaling[i,j])
__global__ void kan_prep(const float* __restrict__ coeff,
                         const float* __restrict__ scaling,
                         unsigned short* __restrict__ Wt) {
  int idx = blockIdx.x * 256 + threadIdx.x;  // i*512 + j
  int i = idx >> 9, j = idx & 511;
  float s = scaling[idx];
  const float4* cp = reinterpret_cast<const float4*>(coeff) + (size_t)idx * 2;
  float4 c0 = cp[0], c1 = cp[1];
  short8 h;
  h[0] = (short)f2bf(c0.x * s); h[1] = (short)f2bf(c0.y * s);
  h[2] = (short)f2bf(c0.z * s); h[3] = (short)f2bf(c0.w * s);
  h[4] = (short)f2bf(c1.x * s); h[5] = (short)f2bf(c1.y * s);
  h[6] = (short)f2bf(c1.z * s); h[7] = (short)f2bf(c1.w * s);
  *reinterpret_cast<short8*>(Wt + (size_t)j * KDIM + i * 8) = h;
}

// ---- fused-basis single-barrier 64x64x64 GEMM, depth-4 rings -------------
// 256 thr = 4 waves (2x2), wave tile 32x32 (2x2 of 16x16x32). 1-D grid of
// 512 blocks: row-tile = b%64 (XCD = b%8: row's x/out pinned to one L2),
// col-tile = b/64. LDS rows XOR-swizzled in 16B chunks: slot s of row r
// holds chunk s^(r&7) (B: swizzle on the global gather address; A: on the
// ds_write address). Measured 0 bank conflicts (R6/R7).
__global__ __launch_bounds__(256, 2)
void kan_gemm_p(const float* __restrict__ x,
                const unsigned short* __restrict__ Wt,
                float* __restrict__ out) {
  __shared__ unsigned short As[4][64 * 64];   // 4 x 8 KB
  __shared__ unsigned short Bs[4][64 * 64];   // 4 x 8 KB
  __shared__ float          Xs[4][512];       // 4 x 2 KB

  const int tid  = threadIdx.x;
  const int lane = tid & 63;
  const int wid  = tid >> 6;
  const int wm = wid >> 1, wn = wid & 1;
  const int ln = lane & 15, quad = lane >> 4;

  const int b    = blockIdx.x;
  const int row0 = (b & 63) * 64;           // XCD-pinning key (XCD = b%8)
  const int col0 = (b >> 6) * 64;

  f32x4 acc[2][2] = {};

  const int lr = lane >> 3;                 // B staging row within 8-row inst
  const int cg = (lane & 7) ^ lr;           // XOR-swizzled 16B chunk to fetch
  const unsigned short* bRow = Wt + (size_t)(col0 + wid * 16 + lr) * KDIM + cg * 8;

  // A-compute: thread -> row rn = lane, chunks wid*2, wid*2+1
  const int rn  = lane;
  const int sw0 = ((wid * 2)     ^ (rn & 7)) * 8;
  const int sw1 = ((wid * 2 + 1) ^ (rn & 7)) * 8;

  // B tile kt -> stage st: 2 resultless DMA insts per wave (16 KB total/blk)
  auto issueB = [&](int kt, int st) {
    const int k0 = kt * 64;
#pragma unroll
    for (int t = 0; t < 2; ++t) {
      const int rbase = wid * 16 + t * 8;                      // wave-uniform
      async_load16(bRow + (size_t)t * 8 * KDIM + k0, &Bs[st][rbase * 64]);
    }
  };

  // x tile kt (64 rows x 8 floats = 2 KB) -> X stage: 2 DMA insts per wave
  auto issueX = [&](int kt, int st) {
#pragma unroll
    for (int p = 0; p < 2; ++p) {
      const int f = wid * 128 + p * 64 + lane;                 // 0..511
      const float* ga = x + (size_t)(row0 + (f >> 3)) * IN_DIM + kt * 8 + (f & 7);
      async_load4(ga, &Xs[st][wid * 128 + p * 64]);            // +lane*4 implicit
    }
  };

  // basis for tile (stage st): read x pair from X stage, write A stage
  auto computeA = [&](int st) {
    float2 xv = *reinterpret_cast<const float2*>(&Xs[st][rn * 8 + wid * 2]);
    short8 h0 = basis_pack8(xv.x);
    short8 h1 = basis_pack8(xv.y);
    *reinterpret_cast<short8*>(&As[st][rn * 64 + sw0]) = h0;
    *reinterpret_cast<short8*>(&As[st][rn * 64 + sw1]) = h1;
  };

  auto compute = [&](int st) {
#pragma unroll
    for (int kk = 0; kk < 2; ++kk) {
      short8 af[2], bfr[2];
#pragma unroll
      for (int mt = 0; mt < 2; ++mt) {
        const int r    = wm * 32 + mt * 16 + ln;
        const int slot = (kk * 4 + quad) ^ (r & 7);
        af[mt] = *reinterpret_cast<const short8*>(&As[st][r * 64 + slot * 8]);
      }
#pragma unroll
      for (int nt = 0; nt < 2; ++nt) {
        const int c    = wn * 32 + nt * 16 + ln;
        const int slot = (kk * 4 + quad) ^ (c & 7);
        bfr[nt] = *reinterpret_cast<const short8*>(&Bs[st][c * 64 + slot * 8]);
      }
#pragma unroll
      for (int mt = 0; mt < 2; ++mt)
#pragma unroll
        for (int nt = 0; nt < 2; ++nt)
          acc[mt][nt] = __builtin_amdgcn_mfma_f32_16x16x32_bf16(af[mt], bfr[nt], acc[mt][nt], 0, 0, 0);
    }
  };

  // ---- prologue (stream: X0 X1 X2 B0 | X3 B1 | X4 B2; waits verified) ----
  issueX(0, 0); issueX(1, 1);
  issueX(2, 2); issueB(0, 0);
  __builtin_amdgcn_s_waitcnt(W_VM6_LG0);   // X0 retired (6 younger ops)
  __builtin_amdgcn_s_barrier();
  computeA(0);
  issueX(3, 3); issueB(1, 1);
  __builtin_amdgcn_s_waitcnt(W_VM8_LG0);   // X1 retired (8 younger)
  __builtin_amdgcn_s_barrier();
  computeA(1);
  issueX(4, 0); issueB(2, 2);
  __builtin_amdgcn_s_waitcnt(W_VM10_LG0);  // X2 retired (10 younger)
  __builtin_amdgcn_s_barrier();
  computeA(2);

  // ---- uniform main loop k=0..63 -----------------------------------------
  // At iter-k wait: outstanding = B(k)ab X(k+3)ab B(k+1)ab X(k+4)ab B(k+2)ab
  // -> vm(6) retires B(k) and X(k+3). Clamped issues keep counts uniform.
  int st = 0;
  for (int kt = 0; kt < NKT; ++kt) {
    __builtin_amdgcn_s_waitcnt(W_VM6_LG0);
    __builtin_amdgcn_s_barrier();
    const int kx = (kt + 5 < NKT) ? kt + 5 : NKT - 1;
    const int kb = (kt + 3 < NKT) ? kt + 3 : NKT - 1;
    issueX(kx, (kt + 5) & 3);
    issueB(kb, (kt + 3) & 3);
    computeA((kt + 3) & 3);
    compute(st);
    st = (st + 1) & 3;
  }

  // C/D layout: col = lane&15, row = quad*4 + reg  (m89/m91-verified)
#pragma unroll
  for (int mt = 0; mt < 2; ++mt)
#pragma unroll
    for (int nt = 0; nt < 2; ++nt) {
      const int col = col0 + wn * 32 + nt * 16 + ln;
#pragma unroll
      for (int r = 0; r < 4; ++r) {
        const int row = row0 + wm * 32 + mt * 16 + quad * 4 + r;
        out[(size_t)row * OUT_DIM + col] = acc[mt][nt][r];
      }
    }
}

// ---- fallback (no ws): on-the-fly staging, 64-tile, direct store ---------
__global__ __launch_bounds__(256, 2)
void kan_gemm_fb(const float* __restrict__ x, const float* __restrict__ coeff,
                 const float* __restrict__ scaling, float* __restrict__ out) {
  __shared__ unsigned short As[64 * 64];
  __shared__ unsigned short Bs[64 * 64];

  const int tid  = threadIdx.x;
  const int lane = tid & 63;
  const int wid  = tid >> 6;
  const int wm = wid >> 1, wn = wid & 1;
  const int ln = lane & 15, quad = lane >> 4;
  const int row0 = blockIdx.y * 64;
  const int col0 = blockIdx.x * 64;

  f32x4 acc[2][2] = {};

  for (int kt = 0; kt < KDIM / 64; ++kt) {
#pragma unroll
    for (int pp = 0; pp < 2; ++pp) {
      const int p  = tid + pp * 256;
      const int rn = p & 63;
      const int il = p >> 6;
      const int sw = ((il ^ (rn & 7)) * 8);
      short8 ha = basis_pack8(x[(size_t)(row0 + rn) * IN_DIM + kt * 8 + il]);
      *reinterpret_cast<short8*>(&As[rn * 64 + sw]) = ha;
      const float* cbase = coeff + (size_t)(kt * 8 + il) * 4096 + (size_t)(col0 + rn) * 8;
      float4 c0 = reinterpret_cast<const float4*>(cbase)[0];
      float4 c1 = reinterpret_cast<const float4*>(cbase)[1];
      float s = scaling[(size_t)(kt * 8 + il) * OUT_DIM + col0 + rn];
      short8 hb;
      hb[0] = (short)f2bf(c0.x * s); hb[1] = (short)f2bf(c0.y * s);
      hb[2] = (short)f2bf(c0.z * s); hb[3] = (short)f2bf(c0.w * s);
      hb[4] = (short)f2bf(c1.x * s); hb[5] = (short)f2bf(c1.y * s);
      hb[6] = (short)f2bf(c1.z * s); hb[7] = (short)f2bf(c1.w * s);
      *reinterpret_cast<short8*>(&Bs[rn * 64 + sw]) = hb;
    }
    __syncthreads();
#pragma unroll
    for (int kk = 0; kk < 2; ++kk) {
      short8 af[2], bfr[2];
#pragma unroll
      for (int mt = 0; mt < 2; ++mt) {
        const int r  = wm * 32 + mt * 16 + ln;
        const int pc = (kk * 4 + quad) ^ (r & 7);
        af[mt] = *reinterpret_cast<const short8*>(&As[r * 64 + pc * 8]);
      }
#pragma unroll
      for (int nt = 0; nt < 2; ++nt) {
        const int c  = wn * 32 + nt * 16 + ln;
        const int pc = (kk * 4 + quad) ^ (c & 7);
        bfr[nt] = *reinterpret_cast<const short8*>(&Bs[c * 64 + pc * 8]);
      }
#pragma unroll
      for (int mt = 0; mt < 2; ++mt)
#pragma unroll
        for (int nt = 0; nt < 2; ++nt)
          acc[mt][nt] = __builtin_amdgcn_mfma_f32_16x16x32_bf16(af[mt], bfr[nt], acc[mt][nt], 0, 0, 0);
    }
    __syncthreads();
  }
#pragma unroll
  for (int mt = 0; mt < 2; ++mt)
#pragma unroll
    for (int nt = 0; nt < 2; ++nt) {
      const int col = col0 + wn * 32 + nt * 16 + ln;
#pragma unroll
      for (int r = 0; r < 4; ++r) {
        const int row = row0 + wm * 32 + mt * 16 + quad * 4 + r;
        out[(size_t)row * OUT_DIM + col] = acc[mt][nt][r];
      }
    }
}

// ---- launch ------------------------------------------------------------
extern "C" void kernel_launch(void* const* d_in, const int* in_sizes, int n_in,
                              void* d_out, int out_size, void* d_ws, size_t ws_size,
                              hipStream_t stream) {
  const float* x       = (const float*)d_in[0];
  const float* coeff   = (const float*)d_in[1];
  const float* scaling = (const float*)d_in[2];
  float* out = (float*)d_out;

  const size_t needW = (size_t)OUT_DIM * KDIM * 2;   // 4 MB bf16 W^T

  if (ws_size >= needW) {
    unsigned short* Wt = (unsigned short*)d_ws;
    kan_prep<<<(IN_DIM * OUT_DIM) / 256, 256, 0, stream>>>(coeff, scaling, Wt);
    kan_gemm_p<<<(BATCH / 64) * (OUT_DIM / 64), 256, 0, stream>>>(x, Wt, out);
  } else {
    kan_gemm_fb<<<dim3(OUT_DIM / 64, BATCH / 64), 256, 0, stream>>>(x, coeff, scaling, out);
  }
}

// Round 9
// 107.726 us; speedup vs baseline: 1.1847x; 1.0685x over previous
//
#include <hip/hip_runtime.h>
#include <hip/hip_bf16.h>
#include <stdint.h>

// KANExpert: out[b,j] = sum_{i,g} basis(x[b,i])[g] * coeff[i,j,g] * scaling[i,j]
// == GEMM M=4096(batch) N=512(out) K=4096(=512 in_dim * 8 basis), bf16 MFMA.
//
// R9: R8's single-barrier all-DMA ring was right but VALU-bloated (763 cyc/
// SIMD-iter issue; addressing recompute + basis convoyed ahead of MFMA).
// Fixes: (1) 4x-unrolled main loop -> ring stages compile-time, LDS addrs
// hoisted to iter-invariant VGPRs + immediates; (2) strength-reduced global
// addrs (thread base ptr + scalar kt offset); (3) MFMA issued BEFORE basis
// per iter so basis VALU overlaps matrix-pipe execution (anti-convoy).
// Protocol unchanged from R8 (verified): wait vm(6) lgkm(0); barrier;
// issueX(k+5); issueB(k+3); compute(k); computeA(k+3). Clamped tail issues.

#define BATCH   4096
#define IN_DIM  512
#define OUT_DIM 512
#define KDIM    (IN_DIM * 8)   // 4096
#define NKT     (KDIM / 64)    // 64 K-tiles

typedef short short8 __attribute__((ext_vector_type(8)));
typedef float f32x4  __attribute__((ext_vector_type(4)));

// s_waitcnt simm16 (gfx9): vmcnt[3:0] | expcnt[6:4] | lgkmcnt[11:8]
#define W_VM6_LG0  0x076
#define W_VM8_LG0  0x078
#define W_VM10_LG0 0x07A

// float -> bf16 bits, round-to-nearest-even (prep only)
__device__ __forceinline__ unsigned int f2bf(float f) {
  union { float f; unsigned int u; } v; v.f = f;
  unsigned int r = v.u + 0x7FFFu + ((v.u >> 16) & 1u);
  return r >> 16;
}

// All 8 basis values of one (b,i), truncating bf16 pack (~28 VALU inst).
// Uniform cubic B-spline, h=0.4: m = min((int)(x*2.5+2.5), 4), u in [0,1];
// window w0..w3 placed at slots m-3..m via branchless 64-bit shift.
__device__ __forceinline__ short8 basis_pack8(float xv) {
  float t = __builtin_fmaf(xv, 2.5f, 2.5f);
  int m = (int)t;                       // t >= 0 -> trunc == floor
  m = m > 4 ? 4 : m;
  float u  = t - (float)m;
  float u2 = u * u, u3 = u2 * u, om = 1.0f - u;
  float om2 = om * om;
  float w0 = om2 * om * (1.0f / 6.0f);
  float w1 = __builtin_fmaf(u3, 0.5f, __builtin_fmaf(u2, -1.0f, 2.0f / 3.0f));
  float s  = (u2 - u3) + u;
  float w2 = __builtin_fmaf(s, 0.5f, 1.0f / 6.0f);
  float w3 = u3 * (1.0f / 6.0f);
  unsigned d0 = __builtin_amdgcn_perm(__float_as_uint(w1), __float_as_uint(w0), 0x07060302u);
  unsigned d1 = __builtin_amdgcn_perm(__float_as_uint(w3), __float_as_uint(w2), 0x07060302u);
  uint64_t wp = ((uint64_t)d1 << 32) | d0;
  int sh = m * 16 - 48;                 // {-48,-32,-16,0,16}
  uint64_t lo = (sh >= 0) ? (wp << sh) : (wp >> (-sh));
  unsigned hi = (sh > 0) ? (unsigned)(wp >> (64 - sh)) : 0u;
  union { unsigned d[4]; short8 s8; } r;
  r.d[0] = (unsigned)lo; r.d[1] = (unsigned)(lo >> 32); r.d[2] = hi; r.d[3] = 0u;
  return r.s8;
}

__device__ __forceinline__ void async_load16(const void* g, void* l) {
  __builtin_amdgcn_global_load_lds(
      (__attribute__((address_space(1))) void*)(uintptr_t)g,
      (__attribute__((address_space(3))) void*)(unsigned int)(uintptr_t)l,
      16, 0, 0);
}
__device__ __forceinline__ void async_load4(const void* g, void* l) {
  __builtin_amdgcn_global_load_lds(
      (__attribute__((address_space(1))) void*)(uintptr_t)g,
      (__attribute__((address_space(3))) void*)(unsigned int)(uintptr_t)l,
      4, 0, 0);
}

// ---- precompute W^T: Wt[j*4096 + i*8 + g] = bf16(coeff[i,j,g]*scaling[i,j])
__global__ void kan_prep(const float* __restrict__ coeff,
                         const float* __restrict__ scaling,
                         unsigned short* __restrict__ Wt) {
  int idx = blockIdx.x * 256 + threadIdx.x;  // i*512 + j
  int i = idx >> 9, j = idx & 511;
  float s = scaling[idx];
  const float4* cp = reinterpret_cast<const float4*>(coeff) + (size_t)idx * 2;
  float4 c0 = cp[0], c1 = cp[1];
  short8 h;
  h[0] = (short)f2bf(c0.x * s); h[1] = (short)f2bf(c0.y * s);
  h[2] = (short)f2bf(c0.z * s); h[3] = (short)f2bf(c0.w * s);
  h[4] = (short)f2bf(c1.x * s); h[5] = (short)f2bf(c1.y * s);
  h[6] = (short)f2bf(c1.z * s); h[7] = (short)f2bf(c1.w * s);
  *reinterpret_cast<short8*>(Wt + (size_t)j * KDIM + i * 8) = h;
}

// ---- fused-basis single-barrier 64x64x64 GEMM, depth-4 rings -------------
// 256 thr = 4 waves (2x2), wave tile 32x32 (2x2 of 16x16x32). 1-D grid of
// 512 blocks: row-tile = b%64 (XCD = b%8: row's x/out pinned to one L2),
// col-tile = b/64. LDS rows XOR-swizzled in 16B chunks.
__global__ __launch_bounds__(256, 2)
void kan_gemm_p(const float* __restrict__ x,
                const unsigned short* __restrict__ Wt,
                float* __restrict__ out) {
  __shared__ unsigned short As[4][64 * 64];   // 4 x 8 KB
  __shared__ unsigned short Bs[4][64 * 64];   // 4 x 8 KB
  __shared__ float          Xs[4][512];       // 4 x 2 KB

  const int tid  = threadIdx.x;
  const int lane = tid & 63;
  const int wid  = tid >> 6;
  const int wm = wid >> 1, wn = wid & 1;
  const int ln = lane & 15, quad = lane >> 4;

  const int b    = blockIdx.x;
  const int row0 = (b & 63) * 64;           // XCD-pinning key (XCD = b%8)
  const int col0 = (b >> 6) * 64;

  f32x4 acc[2][2] = {};

  // ---- iter-invariant addresses (hoisted; per-iter adds are scalar) ------
  const int lr = lane >> 3;
  const int cg = (lane & 7) ^ lr;
  const unsigned short* bBase0 = Wt + (size_t)(col0 + wid * 16 + lr) * KDIM + cg * 8;
  const unsigned short* bBase1 = bBase0 + (size_t)8 * KDIM;

  const int f0 = wid * 128 + lane;          // X gather element ids
  const int f1 = f0 + 64;
  const float* xBase0 = x + (size_t)(row0 + (f0 >> 3)) * IN_DIM + (f0 & 7);
  const float* xBase1 = x + (size_t)(row0 + (f1 >> 3)) * IN_DIM + (f1 & 7);

  const int rn  = lane;                     // computeA: row rn, chunks wid*2,+1
  const int sw0 = ((wid * 2)     ^ (rn & 7)) * 8;
  const int sw1 = ((wid * 2 + 1) ^ (rn & 7)) * 8;

  // compute(): 8 LDS offsets, iter-invariant (stage base folds to immediate)
  int aoff[2][2], boff[2][2];               // [kk][mt/nt] element offsets
#pragma unroll
  for (int kk = 0; kk < 2; ++kk) {
#pragma unroll
    for (int mt = 0; mt < 2; ++mt) {
      const int r = wm * 32 + mt * 16 + ln;
      aoff[kk][mt] = r * 64 + (((kk * 4 + quad) ^ (r & 7)) * 8);
      const int c = wn * 32 + mt * 16 + ln;
      boff[kk][mt] = c * 64 + (((kk * 4 + quad) ^ (c & 7)) * 8);
    }
  }

  auto issueB = [&](int kt, int st) {
    const int k0 = kt * 64;
    async_load16(bBase0 + k0, &Bs[st][(wid * 16) * 64]);
    async_load16(bBase1 + k0, &Bs[st][(wid * 16 + 8) * 64]);
  };
  auto issueX = [&](int kt, int st) {
    async_load4(xBase0 + kt * 8, &Xs[st][wid * 128]);
    async_load4(xBase1 + kt * 8, &Xs[st][wid * 128 + 64]);
  };
  auto computeA = [&](float2 xv, int st) {
    short8 h0 = basis_pack8(xv.x);
    short8 h1 = basis_pack8(xv.y);
    *reinterpret_cast<short8*>(&As[st][rn * 64 + sw0]) = h0;
    *reinterpret_cast<short8*>(&As[st][rn * 64 + sw1]) = h1;
  };
  auto compute = [&](int st) {
#pragma unroll
    for (int kk = 0; kk < 2; ++kk) {
      short8 af[2], bfr[2];
#pragma unroll
      for (int mt = 0; mt < 2; ++mt)
        af[mt] = *reinterpret_cast<const short8*>(&As[st][aoff[kk][mt]]);
#pragma unroll
      for (int nt = 0; nt < 2; ++nt)
        bfr[nt] = *reinterpret_cast<const short8*>(&Bs[st][boff[kk][nt]]);
#pragma unroll
      for (int mt = 0; mt < 2; ++mt)
#pragma unroll
        for (int nt = 0; nt < 2; ++nt)
          acc[mt][nt] = __builtin_amdgcn_mfma_f32_16x16x32_bf16(af[mt], bfr[nt], acc[mt][nt], 0, 0, 0);
    }
  };

  // ---- prologue (identical protocol to R8; in-order vm counts verified) --
  issueX(0, 0); issueX(1, 1);
  issueX(2, 2); issueB(0, 0);
  __builtin_amdgcn_s_waitcnt(W_VM6_LG0);   // X0 retired
  __builtin_amdgcn_s_barrier();
  { float2 xv = *reinterpret_cast<const float2*>(&Xs[0][rn * 8 + wid * 2]); computeA(xv, 0); }
  issueX(3, 3); issueB(1, 1);
  __builtin_amdgcn_s_waitcnt(W_VM8_LG0);   // X1 retired
  __builtin_amdgcn_s_barrier();
  { float2 xv = *reinterpret_cast<const float2*>(&Xs[1][rn * 8 + wid * 2]); computeA(xv, 1); }
  issueX(4, 0); issueB(2, 2);
  __builtin_amdgcn_s_waitcnt(W_VM10_LG0);  // X2 retired
  __builtin_amdgcn_s_barrier();
  { float2 xv = *reinterpret_cast<const float2*>(&Xs[2][rn * 8 + wid * 2]); computeA(xv, 2); }

  // ---- main loop: 16 groups x 4 (ring stages compile-time) ---------------
  // At iter-k wait: outstanding = B(k) X(k+3) B(k+1) X(k+4) B(k+2) (10 ops);
  // vm(6) retires B(k)+X(k+3). lgkm(0): own prior ds ops done before barrier.
  for (int g = 0; g < 16; ++g) {
#pragma unroll
    for (int s = 0; s < 4; ++s) {
      const int kt = g * 4 + s;            // kt & 3 == s
      __builtin_amdgcn_s_waitcnt(W_VM6_LG0);
      __builtin_amdgcn_s_barrier();
      // x for tile k+3 (stage (s+3)&3) -- hoisted so latency hides under MFMA
      float2 xv = *reinterpret_cast<const float2*>(&Xs[(s + 3) & 3][rn * 8 + wid * 2]);
      const int kx = (kt + 5 < NKT) ? kt + 5 : NKT - 1;
      const int kb = (kt + 3 < NKT) ? kt + 3 : NKT - 1;
      issueX(kx, (s + 1) & 3);             // (kt+5)&3 == (s+1)&3
      issueB(kb, (s + 3) & 3);
      compute(s);                          // MFMA first (anti-convoy)
      computeA(xv, (s + 3) & 3);           // basis overlaps matrix pipe
    }
  }

  // C/D layout: col = lane&15, row = quad*4 + reg  (m89/m91-verified)
#pragma unroll
  for (int mt = 0; mt < 2; ++mt)
#pragma unroll
    for (int nt = 0; nt < 2; ++nt) {
      const int col = col0 + wn * 32 + nt * 16 + ln;
#pragma unroll
      for (int r = 0; r < 4; ++r) {
        const int row = row0 + wm * 32 + mt * 16 + quad * 4 + r;
        out[(size_t)row * OUT_DIM + col] = acc[mt][nt][r];
      }
    }
}

// ---- fallback (no ws): on-the-fly staging, 64-tile, direct store ---------
__global__ __launch_bounds__(256, 2)
void kan_gemm_fb(const float* __restrict__ x, const float* __restrict__ coeff,
                 const float* __restrict__ scaling, float* __restrict__ out) {
  __shared__ unsigned short As[64 * 64];
  __shared__ unsigned short Bs[64 * 64];

  const int tid  = threadIdx.x;
  const int lane = tid & 63;
  const int wid  = tid >> 6;
  const int wm = wid >> 1, wn = wid & 1;
  const int ln = lane & 15, quad = lane >> 4;
  const int row0 = blockIdx.y * 64;
  const int col0 = blockIdx.x * 64;

  f32x4 acc[2][2] = {};

  for (int kt = 0; kt < KDIM / 64; ++kt) {
#pragma unroll
    for (int pp = 0; pp < 2; ++pp) {
      const int p  = tid + pp * 256;
      const int rn = p & 63;
      const int il = p >> 6;
      const int sw = ((il ^ (rn & 7)) * 8);
      short8 ha = basis_pack8(x[(size_t)(row0 + rn) * IN_DIM + kt * 8 + il]);
      *reinterpret_cast<short8*>(&As[rn * 64 + sw]) = ha;
      const float* cbase = coeff + (size_t)(kt * 8 + il) * 4096 + (size_t)(col0 + rn) * 8;
      float4 c0 = reinterpret_cast<const float4*>(cbase)[0];
      float4 c1 = reinterpret_cast<const float4*>(cbase)[1];
      float s = scaling[(size_t)(kt * 8 + il) * OUT_DIM + col0 + rn];
      short8 hb;
      hb[0] = (short)f2bf(c0.x * s); hb[1] = (short)f2bf(c0.y * s);
      hb[2] = (short)f2bf(c0.z * s); hb[3] = (short)f2bf(c0.w * s);
      hb[4] = (short)f2bf(c1.x * s); hb[5] = (short)f2bf(c1.y * s);
      hb[6] = (short)f2bf(c1.z * s); hb[7] = (short)f2bf(c1.w * s);
      *reinterpret_cast<short8*>(&Bs[rn * 64 + sw]) = hb;
    }
    __syncthreads();
#pragma unroll
    for (int kk = 0; kk < 2; ++kk) {
      short8 af[2], bfr[2];
#pragma unroll
      for (int mt = 0; mt < 2; ++mt) {
        const int r  = wm * 32 + mt * 16 + ln;
        const int pc = (kk * 4 + quad) ^ (r & 7);
        af[mt] = *reinterpret_cast<const short8*>(&As[r * 64 + pc * 8]);
      }
#pragma unroll
      for (int nt = 0; nt < 2; ++nt) {
        const int c  = wn * 32 + nt * 16 + ln;
        const int pc = (kk * 4 + quad) ^ (c & 7);
        bfr[nt] = *reinterpret_cast<const short8*>(&Bs[c * 64 + pc * 8]);
      }
#pragma unroll
      for (int mt = 0; mt < 2; ++mt)
#pragma unroll
        for (int nt = 0; nt < 2; ++nt)
          acc[mt][nt] = __builtin_amdgcn_mfma_f32_16x16x32_bf16(af[mt], bfr[nt], acc[mt][nt], 0, 0, 0);
    }
    __syncthreads();
  }
#pragma unroll
  for (int mt = 0; mt < 2; ++mt)
#pragma unroll
    for (int nt = 0; nt < 2; ++nt) {
      const int col = col0 + wn * 32 + nt * 16 + ln;
#pragma unroll
      for (int r = 0; r < 4; ++r) {
        const int row = row0 + wm * 32 + mt * 16 + quad * 4 + r;
        out[(size_t)row * OUT_DIM + col] = acc[mt][nt][r];
      }
    }
}

// ---- launch ------------------------------------------------------------
extern "C" void kernel_launch(void* const* d_in, const int* in_sizes, int n_in,
                              void* d_out, int out_size, void* d_ws, size_t ws_size,
                              hipStream_t stream) {
  const float* x       = (const float*)d_in[0];
  const float* coeff   = (const float*)d_in[1];
  const float* scaling = (const float*)d_in[2];
  float* out = (float*)d_out;

  const size_t needW = (size_t)OUT_DIM * KDIM * 2;   // 4 MB bf16 W^T

  if (ws_size >= needW) {
    unsigned short* Wt = (unsigned short*)d_ws;
    kan_prep<<<(IN_DIM * OUT_DIM) / 256, 256, 0, stream>>>(coeff, scaling, Wt);
    kan_gemm_p<<<(BATCH / 64) * (OUT_DIM / 64), 256, 0, stream>>>(x, Wt, out);
  } else {
    kan_gemm_fb<<<dim3(OUT_DIM / 64, BATCH / 64), 256, 0, stream>>>(x, coeff, scaling, out);
  }
}